// Round 1
// baseline (238.527 us; speedup 1.0000x reference)
//
#include <hip/hip_runtime.h>
#include <hip/hip_bf16.h>
#include <cstdint>
#include <cstddef>

// Problem constants (reference: B=4096, D=256, T=0.5)
#define BSZ   4096
#define NROW  8192          // 2*B
#define DIM   256
#define INV_T 2.0f
#define EPS_N 1e-8f

typedef __attribute__((ext_vector_type(8))) short bf16x8;   // 8 bf16 = 4 VGPRs
typedef __attribute__((ext_vector_type(4))) float f32x4;

// ---------------------------------------------------------------------------
// async global->LDS 16B helper (wave-uniform LDS base + lane*16 layout)
__device__ __forceinline__ void load_lds16(const void* g, void* l) {
    __builtin_amdgcn_global_load_lds(
        (const __attribute__((address_space(1))) void*)g,
        (__attribute__((address_space(3))) void*)l,
        16, 0, 0);
}

// ---------------------------------------------------------------------------
// Kernel 1: row-normalize concat(z1,z2) in fp32, store bf16 Zn [NROW][DIM]
__global__ void nt_normalize(const float* __restrict__ z1,
                             const float* __restrict__ z2,
                             __hip_bfloat16* __restrict__ zn) {
    const int row = blockIdx.x;
    const int tid = threadIdx.x;            // 256 threads = DIM
    const float* src = (row < BSZ) ? (z1 + (size_t)row * DIM)
                                   : (z2 + (size_t)(row - BSZ) * DIM);
    float v = src[tid];
    float ss = v * v;
    #pragma unroll
    for (int off = 32; off; off >>= 1) ss += __shfl_xor(ss, off);
    __shared__ float red[4];
    __shared__ float rinv_s;
    if ((tid & 63) == 0) red[tid >> 6] = ss;
    __syncthreads();
    if (tid == 0) {
        float s = red[0] + red[1] + red[2] + red[3];
        rinv_s = 1.0f / fmaxf(sqrtf(s), EPS_N);   // torch cosine-sim eps clamp
    }
    __syncthreads();
    zn[(size_t)row * DIM + tid] = __float2bfloat16(v * rinv_s);
}

// ---------------------------------------------------------------------------
// Kernel 2: tiled Zn·Znᵀ with fused exp-rowsum. Each block: 128x128 tile.
// 256 threads = 4 waves in 2x2, each wave a 64x64 subtile via 4x4 MFMA 16x16x32.
__global__ __launch_bounds__(256)
void nt_gram(const __hip_bfloat16* __restrict__ zn,
             float* __restrict__ rowsum) {
    __shared__ __hip_bfloat16 As[128 * 64];   // 16 KB, row-major [128][64]
    __shared__ __hip_bfloat16 Bs[128 * 64];   // 16 KB

    const int bi = blockIdx.x, bj = blockIdx.y;
    const int t    = threadIdx.x;
    const int lane = t & 63;
    const int wave = t >> 6;
    const int wrow = (wave >> 1) * 64;
    const int wcol = (wave & 1) * 64;

    f32x4 acc[4][4] = {};

    const __hip_bfloat16* Ag = zn + (size_t)bi * 128 * DIM;
    const __hip_bfloat16* Bg = zn + (size_t)bj * 128 * DIM;

    const int srow  = t >> 3;       // 0..31 per pass
    const int schnk = t & 7;        // 8 chunks of 8 bf16 per 64-col row

    for (int k0 = 0; k0 < DIM; k0 += 64) {
        #pragma unroll
        for (int p = 0; p < 4; ++p) {
            const int row = p * 32 + srow;
            load_lds16(Ag + (size_t)row * DIM + k0 + schnk * 8,
                       (char*)As + p * 4096 + t * 16);
            load_lds16(Bg + (size_t)row * DIM + k0 + schnk * 8,
                       (char*)Bs + p * 4096 + t * 16);
        }
        __syncthreads();

        const int q   = lane >> 4;
        const int r16 = lane & 15;
        #pragma unroll
        for (int kk = 0; kk < 64; kk += 32) {
            bf16x8 af[4], bfr[4];
            #pragma unroll
            for (int mi = 0; mi < 4; ++mi) {
                const int m = wrow + mi * 16 + r16;
                af[mi] = *(const bf16x8*)((const char*)As + m * 128 + kk * 2 + q * 16);
            }
            #pragma unroll
            for (int ni = 0; ni < 4; ++ni) {
                const int n = wcol + ni * 16 + r16;
                bfr[ni] = *(const bf16x8*)((const char*)Bs + n * 128 + kk * 2 + q * 16);
            }
            #pragma unroll
            for (int mi = 0; mi < 4; ++mi)
                #pragma unroll
                for (int ni = 0; ni < 4; ++ni)
                    acc[mi][ni] = __builtin_amdgcn_mfma_f32_16x16x32_bf16(
                        af[mi], bfr[ni], acc[mi][ni], 0, 0, 0);
        }
        __syncthreads();
    }

    // Epilogue: C/D layout col=lane&15, row=quad*4+reg (m89-verified).
    const int q = lane >> 4;
    const int c = lane & 15;
    #pragma unroll
    for (int mi = 0; mi < 4; ++mi) {
        #pragma unroll
        for (int r = 0; r < 4; ++r) {
            const int grow = bi * 128 + wrow + mi * 16 + q * 4 + r;
            float s = 0.f;
            #pragma unroll
            for (int ni = 0; ni < 4; ++ni) {
                const int gcol = bj * 128 + wcol + ni * 16 + c;
                const float e = __expf(acc[mi][ni][r] * INV_T);
                s += (grow == gcol) ? 0.f : e;   // exact diagonal exclusion
            }
            // reduce across the 16 lanes of this quad (all same grow)
            s += __shfl_xor(s, 1);
            s += __shfl_xor(s, 2);
            s += __shfl_xor(s, 4);
            s += __shfl_xor(s, 8);
            if (c == 0) atomicAdd(&rowsum[grow], s);
        }
    }
}

// ---------------------------------------------------------------------------
// Kernel 3: per-row positive dot + loss, atomic-accumulate mean into out[0].
__global__ void nt_finalize(const __hip_bfloat16* __restrict__ zn,
                            const float* __restrict__ rowsum,
                            float* __restrict__ out) {
    const int wave = threadIdx.x >> 6;
    const int lane = threadIdx.x & 63;
    const int row  = blockIdx.x * 4 + wave;
    const int partner = (row < BSZ) ? (row + BSZ) : (row - BSZ);
    const __hip_bfloat16* a = zn + (size_t)row * DIM;
    const __hip_bfloat16* b = zn + (size_t)partner * DIM;
    float p = 0.f;
    #pragma unroll
    for (int j = 0; j < 4; ++j) {
        const int k = lane * 4 + j;
        p += __bfloat162float(a[k]) * __bfloat162float(b[k]);
    }
    #pragma unroll
    for (int off = 32; off; off >>= 1) p += __shfl_xor(p, off);
    if (lane == 0) {
        const float pl  = p * INV_T;
        const float lse = logf(__expf(pl) + rowsum[row]);
        atomicAdd(out, (lse - pl) * (1.0f / NROW));
    }
}

// ---------------------------------------------------------------------------
extern "C" void kernel_launch(void* const* d_in, const int* in_sizes, int n_in,
                              void* d_out, int out_size, void* d_ws, size_t ws_size,
                              hipStream_t stream) {
    const float* z1 = (const float*)d_in[0];
    const float* z2 = (const float*)d_in[1];
    float* out = (float*)d_out;

    __hip_bfloat16* zn = (__hip_bfloat16*)d_ws;                       // 4 MB
    float* rowsum = (float*)((char*)d_ws + (size_t)NROW * DIM * 2);   // 32 KB

    hipMemsetAsync(rowsum, 0, NROW * sizeof(float), stream);
    hipMemsetAsync(out, 0, sizeof(float), stream);

    nt_normalize<<<NROW, 256, 0, stream>>>(z1, z2, zn);
    dim3 grid(NROW / 128, NROW / 128);
    nt_gram<<<grid, 256, 0, stream>>>(zn, rowsum);
    nt_finalize<<<NROW / 4, 256, 0, stream>>>(zn, rowsum, out);
}

// Round 2
// 115.262 us; speedup vs baseline: 2.0694x; 2.0694x over previous
//
#include <hip/hip_runtime.h>
#include <hip/hip_bf16.h>
#include <cstdint>
#include <cstddef>

// Problem constants (reference: B=4096, D=256, T=0.5)
#define BSZ   4096
#define NROW  8192          // 2*B
#define DIM   256
#define INV_T 2.0f
#define EPS_N 1e-8f

typedef __attribute__((ext_vector_type(8))) short bf16x8;   // 8 bf16 = 4 VGPRs
typedef __attribute__((ext_vector_type(4))) float f32x4;

// ---------------------------------------------------------------------------
// async global->LDS 16B helper (wave-uniform LDS base + lane*16 layout)
__device__ __forceinline__ void load_lds16(const void* g, void* l) {
    __builtin_amdgcn_global_load_lds(
        (const __attribute__((address_space(1))) void*)g,
        (__attribute__((address_space(3))) void*)l,
        16, 0, 0);
}

// ---------------------------------------------------------------------------
// Kernel 1: row-normalize concat(z1,z2) in fp32, store bf16 Zn [NROW][DIM]
__global__ void nt_normalize(const float* __restrict__ z1,
                             const float* __restrict__ z2,
                             __hip_bfloat16* __restrict__ zn) {
    const int row = blockIdx.x;
    const int tid = threadIdx.x;            // 256 threads = DIM
    const float* src = (row < BSZ) ? (z1 + (size_t)row * DIM)
                                   : (z2 + (size_t)(row - BSZ) * DIM);
    float v = src[tid];
    float ss = v * v;
    #pragma unroll
    for (int off = 32; off; off >>= 1) ss += __shfl_xor(ss, off);
    __shared__ float red[4];
    __shared__ float rinv_s;
    if ((tid & 63) == 0) red[tid >> 6] = ss;
    __syncthreads();
    if (tid == 0) {
        float s = red[0] + red[1] + red[2] + red[3];
        rinv_s = 1.0f / fmaxf(sqrtf(s), EPS_N);   // torch cosine-sim eps clamp
    }
    __syncthreads();
    zn[(size_t)row * DIM + tid] = __float2bfloat16(v * rinv_s);
}

// ---------------------------------------------------------------------------
// Kernel 2: tiled Zn·Znᵀ, SYMMETRIC: only tiles bi<=bj computed (2080/4096
// blocks). Off-diag tiles feed exp-sums to rows (bi strip) AND columns
// (bj strip, = transposed rows by symmetry). Positives (offset +-B) live on
// the local diagonal of tiles with bj==bi+32 -> written to pos[] for free.
__global__ __launch_bounds__(256)
void nt_gram(const __hip_bfloat16* __restrict__ zn,
             float* __restrict__ rowsum,
             float* __restrict__ pos) {
    const int bi = blockIdx.x, bj = blockIdx.y;
    if (bi > bj) return;                     // symmetry: upper triangle only

    __shared__ __hip_bfloat16 As[128 * 64];  // 16 KB, row-major [128][64]
    __shared__ __hip_bfloat16 Bs[128 * 64];  // 16 KB

    const int t    = threadIdx.x;
    const int lane = t & 63;
    const int wave = t >> 6;
    const int wrow = (wave >> 1) * 64;
    const int wcol = (wave & 1) * 64;

    f32x4 acc[4][4] = {};

    const __hip_bfloat16* Ag = zn + (size_t)bi * 128 * DIM;
    const __hip_bfloat16* Bg = zn + (size_t)bj * 128 * DIM;

    const int srow  = t >> 3;       // 0..31 per pass
    const int schnk = t & 7;        // 8 chunks of 8 bf16 per 64-col row

    for (int k0 = 0; k0 < DIM; k0 += 64) {
        #pragma unroll
        for (int p = 0; p < 4; ++p) {
            const int row = p * 32 + srow;
            load_lds16(Ag + (size_t)row * DIM + k0 + schnk * 8,
                       (char*)As + p * 4096 + t * 16);
            load_lds16(Bg + (size_t)row * DIM + k0 + schnk * 8,
                       (char*)Bs + p * 4096 + t * 16);
        }
        __syncthreads();

        const int q   = lane >> 4;
        const int r16 = lane & 15;
        #pragma unroll
        for (int kk = 0; kk < 64; kk += 32) {
            bf16x8 af[4], bfr[4];
            #pragma unroll
            for (int mi = 0; mi < 4; ++mi) {
                const int m = wrow + mi * 16 + r16;
                af[mi] = *(const bf16x8*)((const char*)As + m * 128 + kk * 2 + q * 16);
            }
            #pragma unroll
            for (int ni = 0; ni < 4; ++ni) {
                const int n = wcol + ni * 16 + r16;
                bfr[ni] = *(const bf16x8*)((const char*)Bs + n * 128 + kk * 2 + q * 16);
            }
            #pragma unroll
            for (int mi = 0; mi < 4; ++mi)
                #pragma unroll
                for (int ni = 0; ni < 4; ++ni)
                    acc[mi][ni] = __builtin_amdgcn_mfma_f32_16x16x32_bf16(
                        af[mi], bfr[ni], acc[mi][ni], 0, 0, 0);
        }
        __syncthreads();
    }

    // Epilogue. C/D layout: col=lane&15, row=(lane>>4)*4+reg (m89-verified).
    const int q = lane >> 4;
    const int c = lane & 15;
    const bool diag_block = (bi == bj);
    float colp[4] = {0.f, 0.f, 0.f, 0.f};   // per-ni column partial (this lane's col)

    #pragma unroll
    for (int mi = 0; mi < 4; ++mi) {
        #pragma unroll
        for (int r = 0; r < 4; ++r) {
            const int grow = bi * 128 + wrow + mi * 16 + q * 4 + r;
            float s = 0.f;
            #pragma unroll
            for (int ni = 0; ni < 4; ++ni) {
                const int gcol = bj * 128 + wcol + ni * 16 + c;
                const float val = acc[mi][ni][r];
                float e = __expf(val * INV_T);
                e = (grow == gcol) ? 0.f : e;   // exact diagonal exclusion
                s += e;
                colp[ni] += e;
                if (gcol == grow + BSZ) {       // positive pair: tile-diag of bj==bi+32
                    pos[grow] = val;
                    pos[gcol] = val;            // symmetric partner
                }
            }
            // reduce across the 16 lanes of this quad (all same grow)
            s += __shfl_xor(s, 1);
            s += __shfl_xor(s, 2);
            s += __shfl_xor(s, 4);
            s += __shfl_xor(s, 8);
            if (c == 0) atomicAdd(&rowsum[grow], s);
        }
    }
    // Column sums -> rows of the bj strip (symmetry). Skip on diagonal tiles
    // (tile already fully computed there; row sums cover it).
    if (!diag_block) {
        #pragma unroll
        for (int ni = 0; ni < 4; ++ni) {
            float cs = colp[ni];
            cs += __shfl_xor(cs, 16);
            cs += __shfl_xor(cs, 32);
            if (q == 0) atomicAdd(&rowsum[bj * 128 + wcol + ni * 16 + c], cs);
        }
    }
}

// ---------------------------------------------------------------------------
// Kernel 3: per-row loss from pos[] + rowsum[], block-reduce, 1 atomic/block.
__global__ __launch_bounds__(256)
void nt_finalize(const float* __restrict__ rowsum,
                 const float* __restrict__ pos,
                 float* __restrict__ out) {
    const int i = blockIdx.x * 256 + threadIdx.x;   // 32 blocks x 256 = 8192
    const float pl  = pos[i] * INV_T;
    const float lse = logf(__expf(pl) + rowsum[i]);
    float v = (lse - pl) * (1.0f / NROW);
    #pragma unroll
    for (int off = 32; off; off >>= 1) v += __shfl_xor(v, off);
    __shared__ float red[4];
    if ((threadIdx.x & 63) == 0) red[threadIdx.x >> 6] = v;
    __syncthreads();
    if (threadIdx.x == 0)
        atomicAdd(out, red[0] + red[1] + red[2] + red[3]);
}

// ---------------------------------------------------------------------------
extern "C" void kernel_launch(void* const* d_in, const int* in_sizes, int n_in,
                              void* d_out, int out_size, void* d_ws, size_t ws_size,
                              hipStream_t stream) {
    const float* z1 = (const float*)d_in[0];
    const float* z2 = (const float*)d_in[1];
    float* out = (float*)d_out;

    __hip_bfloat16* zn = (__hip_bfloat16*)d_ws;                       // 4 MB
    float* rowsum = (float*)((char*)d_ws + (size_t)NROW * DIM * 2);   // 32 KB
    float* pos    = rowsum + NROW;                                    // 32 KB

    hipMemsetAsync(rowsum, 0, 2 * NROW * sizeof(float), stream);      // rowsum+pos
    hipMemsetAsync(out, 0, sizeof(float), stream);

    nt_normalize<<<NROW, 256, 0, stream>>>(z1, z2, zn);
    dim3 grid(NROW / 128, NROW / 128);
    nt_gram<<<grid, 256, 0, stream>>>(zn, rowsum, pos);
    nt_finalize<<<NROW / 256, 256, 0, stream>>>(rowsum, pos, out);
}

// Round 3
// 105.142 us; speedup vs baseline: 2.2686x; 1.0962x over previous
//
#include <hip/hip_runtime.h>
#include <hip/hip_bf16.h>
#include <cstdint>
#include <cstddef>
#include <math.h>

// Problem constants (reference: B=4096, D=256, T=0.5)
#define BSZ   4096
#define NROW  8192          // 2*B
#define DIM   256
#define INV_T 2.0f
#define EPS_N 1e-8f

typedef __attribute__((ext_vector_type(8))) short bf16x8;   // 8 bf16 = 4 VGPRs
typedef __attribute__((ext_vector_type(4))) float f32x4;

__device__ __forceinline__ unsigned short f2bf(float x) {
    __hip_bfloat16 h = __float2bfloat16(x);
    return __builtin_bit_cast(unsigned short, h);
}

// async global->LDS 16B helper (wave-uniform LDS base + lane*16 layout)
__device__ __forceinline__ void load_lds16(const void* g, void* l) {
    __builtin_amdgcn_global_load_lds(
        (const __attribute__((address_space(1))) void*)g,
        (__attribute__((address_space(3))) void*)l,
        16, 0, 0);
}

// ---------------------------------------------------------------------------
// Kernel 1: row-normalize concat(z1,z2), fp32 math, bf16 out. One row/wave,
// float4 loads (16B/lane), no block barriers. Also zeroes rowsum[row]
// (replaces a hipMemsetAsync dispatch).
__global__ __launch_bounds__(256)
void nt_normalize(const float* __restrict__ z1,
                  const float* __restrict__ z2,
                  __hip_bfloat16* __restrict__ zn,
                  float* __restrict__ rowsum) {
    const int wave = threadIdx.x >> 6;
    const int lane = threadIdx.x & 63;
    const int row  = blockIdx.x * 4 + wave;
    const float* src = (row < BSZ) ? (z1 + (size_t)row * DIM)
                                   : (z2 + (size_t)(row - BSZ) * DIM);
    const float4 v = ((const float4*)src)[lane];
    float ss = v.x * v.x + v.y * v.y + v.z * v.z + v.w * v.w;
    #pragma unroll
    for (int off = 32; off; off >>= 1) ss += __shfl_xor(ss, off);
    const float rinv = 1.0f / fmaxf(sqrtf(ss), EPS_N);  // torch eps clamp
    ushort4 o;
    o.x = f2bf(v.x * rinv);
    o.y = f2bf(v.y * rinv);
    o.z = f2bf(v.z * rinv);
    o.w = f2bf(v.w * rinv);
    ((ushort4*)(zn + (size_t)row * DIM))[lane] = o;
    if (lane == 0) rowsum[row] = 0.0f;
}

// ---------------------------------------------------------------------------
// Kernel 2: tiled Zn·Znᵀ, upper triangle only (1D triangular grid, 2080
// blocks). LDS XOR-swizzle: LDS[m][pos] holds global chunk pos^(m&7), so
// fragment reads spread over all 32 banks (2-way = free) while the
// global_load_lds lane->slot mapping stays the required identity.
__global__ __launch_bounds__(256)
void nt_gram(const __hip_bfloat16* __restrict__ zn,
             float* __restrict__ rowsum,
             float* __restrict__ pos) {
    // Triangular decode: S(bi) = 64*bi - bi*(bi-1)/2 tiles before row bi.
    const int l = blockIdx.x;
    int bi = (int)((129.0 - sqrt(16641.0 - 8.0 * (double)l)) * 0.5);
    while (64 * (bi + 1) - (bi + 1) * bi / 2 <= l) ++bi;   // fp-edge correction
    while (64 * bi - bi * (bi - 1) / 2 > l) --bi;
    const int bj = bi + (l - (64 * bi - bi * (bi - 1) / 2));

    __shared__ __hip_bfloat16 As[128 * 64];  // 16 KB, [128 rows][8 chunks of 16B]
    __shared__ __hip_bfloat16 Bs[128 * 64];  // 16 KB

    const int t    = threadIdx.x;
    const int lane = t & 63;
    const int wave = t >> 6;
    const int wrow = (wave >> 1) * 64;
    const int wcol = (wave & 1) * 64;

    f32x4 acc[4][4] = {};

    const __hip_bfloat16* Ag = zn + (size_t)bi * 128 * DIM;
    const __hip_bfloat16* Bg = zn + (size_t)bj * 128 * DIM;

    const int srow = t >> 3;                    // 0..31 per pass
    const int sc   = (t & 7) ^ (srow & 7);      // swizzled global chunk
    // note: (p*32 + srow)&7 == srow&7, so sc is pass-invariant

    const int q   = lane >> 4;
    const int r16 = lane & 15;
    const int sw  = r16 & 7;                    // read-side swizzle key (m&7)

    for (int k0 = 0; k0 < DIM; k0 += 64) {
        #pragma unroll
        for (int p = 0; p < 4; ++p) {
            const int row = p * 32 + srow;
            load_lds16(Ag + (size_t)row * DIM + k0 + sc * 8,
                       (char*)As + p * 4096 + t * 16);
            load_lds16(Bg + (size_t)row * DIM + k0 + sc * 8,
                       (char*)Bs + p * 4096 + t * 16);
        }
        __syncthreads();

        #pragma unroll
        for (int kk = 0; kk < 64; kk += 32) {
            const int cc = (kk >> 3) + q;       // chunk index within row
            const int cpos = (cc ^ sw) << 4;    // swizzled byte position
            bf16x8 af[4], bfr[4];
            #pragma unroll
            for (int mi = 0; mi < 4; ++mi) {
                const int m = wrow + mi * 16 + r16;
                af[mi] = *(const bf16x8*)((const char*)As + m * 128 + cpos);
            }
            #pragma unroll
            for (int ni = 0; ni < 4; ++ni) {
                const int n = wcol + ni * 16 + r16;
                bfr[ni] = *(const bf16x8*)((const char*)Bs + n * 128 + cpos);
            }
            #pragma unroll
            for (int mi = 0; mi < 4; ++mi)
                #pragma unroll
                for (int ni = 0; ni < 4; ++ni)
                    acc[mi][ni] = __builtin_amdgcn_mfma_f32_16x16x32_bf16(
                        af[mi], bfr[ni], acc[mi][ni], 0, 0, 0);
        }
        __syncthreads();
    }

    // Epilogue. C/D layout: col=lane&15, row=(lane>>4)*4+reg (m89-verified).
    const int c = lane & 15;
    const bool diag_block = (bi == bj);
    float colp[4] = {0.f, 0.f, 0.f, 0.f};

    #pragma unroll
    for (int mi = 0; mi < 4; ++mi) {
        #pragma unroll
        for (int r = 0; r < 4; ++r) {
            const int grow = bi * 128 + wrow + mi * 16 + q * 4 + r;
            float s = 0.f;
            #pragma unroll
            for (int ni = 0; ni < 4; ++ni) {
                const int gcol = bj * 128 + wcol + ni * 16 + c;
                const float val = acc[mi][ni][r];
                float e = __expf(val * INV_T);
                e = (grow == gcol) ? 0.f : e;   // exact diagonal exclusion
                s += e;
                colp[ni] += e;
                if (gcol == grow + BSZ) {       // positive pair (tile-diag, bj==bi+32)
                    pos[grow] = val;
                    pos[gcol] = val;            // symmetric partner
                }
            }
            s += __shfl_xor(s, 1);
            s += __shfl_xor(s, 2);
            s += __shfl_xor(s, 4);
            s += __shfl_xor(s, 8);
            if (c == 0) atomicAdd(&rowsum[grow], s);
        }
    }
    // Column sums -> bj strip rows (symmetry); skip on diagonal tiles.
    if (!diag_block) {
        #pragma unroll
        for (int ni = 0; ni < 4; ++ni) {
            float cs = colp[ni];
            cs += __shfl_xor(cs, 16);
            cs += __shfl_xor(cs, 32);
            if (q == 0) atomicAdd(&rowsum[bj * 128 + wcol + ni * 16 + c], cs);
        }
    }
}

// ---------------------------------------------------------------------------
// Kernel 3: single block, 1024 threads; writes out[0] directly (no memset,
// no atomic).
__global__ __launch_bounds__(1024)
void nt_finalize(const float* __restrict__ rowsum,
                 const float* __restrict__ pos,
                 float* __restrict__ out) {
    float v = 0.f;
    for (int i = threadIdx.x; i < NROW; i += 1024) {
        const float pl = pos[i] * INV_T;
        v += logf(__expf(pl) + rowsum[i]) - pl;
    }
    #pragma unroll
    for (int off = 32; off; off >>= 1) v += __shfl_xor(v, off);
    __shared__ float red[16];
    if ((threadIdx.x & 63) == 0) red[threadIdx.x >> 6] = v;
    __syncthreads();
    if (threadIdx.x == 0) {
        float s = 0.f;
        #pragma unroll
        for (int w = 0; w < 16; ++w) s += red[w];
        out[0] = s * (1.0f / NROW);
    }
}

// ---------------------------------------------------------------------------
extern "C" void kernel_launch(void* const* d_in, const int* in_sizes, int n_in,
                              void* d_out, int out_size, void* d_ws, size_t ws_size,
                              hipStream_t stream) {
    const float* z1 = (const float*)d_in[0];
    const float* z2 = (const float*)d_in[1];
    float* out = (float*)d_out;

    __hip_bfloat16* zn = (__hip_bfloat16*)d_ws;                       // 4 MB
    float* rowsum = (float*)((char*)d_ws + (size_t)NROW * DIM * 2);   // 32 KB
    float* pos    = rowsum + NROW;                                    // 32 KB (fully overwritten)

    nt_normalize<<<NROW / 4, 256, 0, stream>>>(z1, z2, zn, rowsum);
    nt_gram<<<2080, 256, 0, stream>>>(zn, rowsum, pos);
    nt_finalize<<<1, 1024, 0, stream>>>(rowsum, pos, out);
}